// Round 3
// baseline (2941.857 us; speedup 1.0000x reference)
//
#include <hip/hip_runtime.h>
#include <hip/hip_bf16.h>
#include <stdint.h>

#define N_NODES 50000
#define E_EDGES 800000

typedef short s16x8 __attribute__((ext_vector_type(8)));
typedef float f32x4 __attribute__((ext_vector_type(4)));

__device__ __forceinline__ float bf2f(unsigned int u) {
    return __uint_as_float(u << 16);
}
__device__ __forceinline__ unsigned short f2bf(float f) {
    unsigned int u = __float_as_uint(f);
    unsigned int r = (u + 0x7FFFu + ((u >> 16) & 1u)) >> 16;
    return (unsigned short)r;
}

// ---- scatter: acc[dst[e]][c..c+3] += feat[src[e]][c..c+3] (fp32, 32 thr/edge)
__global__ void scatter_add(const float* __restrict__ feat,
                            const int* __restrict__ src,
                            const int* __restrict__ dst,
                            float* __restrict__ acc, int nthreads) {
    int i = blockIdx.x * blockDim.x + threadIdx.x;
    if (i >= nthreads) return;
    int e = i >> 5;
    int c = (i & 31) * 4;
    int s = src[e];
    int d = dst[e];
    float4 v = *(const float4*)(feat + (size_t)s * 128 + c);
    float* q = acc + (size_t)d * 128 + c;
    unsafeAtomicAdd(q + 0, v.x);
    unsafeAtomicAdd(q + 1, v.y);
    unsafeAtomicAdd(q + 2, v.z);
    unsafeAtomicAdd(q + 3, v.w);
}

// ---- Pre-split weight W[K][F] (fp32 row-major) into hi/lo bf16 MFMA B-frags:
// frag slot i=((t*S+s)*64+lane): element j -> W[s*32+(lane>>4)*8+j][t*16+(lane&15)]
__global__ void prep_w(const float* __restrict__ W,
                       unsigned short* __restrict__ Whi,
                       unsigned short* __restrict__ Wlo,
                       int K, int F, int Fpad) {
    int i = blockIdx.x * blockDim.x + threadIdx.x;
    int S = K / 32, T = Fpad / 16;
    int total = T * S * 64;
    if (i >= total) return;
    int lane = i & 63;
    int s = (i >> 6) % S;
    int t = (i >> 6) / S;
    int col = t * 16 + (lane & 15);
    int k0 = s * 32 + (lane >> 4) * 8;
    s16x8 vh, vl;
#pragma unroll
    for (int j = 0; j < 8; j++) {
        float w = (col < F) ? W[(size_t)(k0 + j) * F + col] : 0.f;
        unsigned short h = f2bf(w);
        float r = w - bf2f(h);
        vh[j] = (short)h;
        vl[j] = (short)f2bf(r);
    }
    *(s16x8*)(Whi + (size_t)i * 8) = vh;
    *(s16x8*)(Wlo + (size_t)i * 8) = vl;
}

// ---- GEMM with bf16 split-precision MFMA (3 mfma per tile).
// A fp32 [N,K]; W pre-split; out fp32 [N,FOUT]; optional ReLU.
template <int K, int F, int FOUT, bool RELU>
__global__ __launch_bounds__(256) void gemm_split(
    const float* __restrict__ A,
    const unsigned short* __restrict__ Whi,
    const unsigned short* __restrict__ Wlo,
    const float* __restrict__ bias,
    float* __restrict__ out) {
    constexpr int S = K / 32;
    constexpr int T = F / 16;
    int wave = threadIdx.x >> 6;
    int lane = threadIdx.x & 63;
    int row0 = blockIdx.x * 64 + wave * 16;
    if (row0 >= N_NODES) return;
    int lm = lane & 15;
    int quad = lane >> 4;

    f32x4 acc[T];
#pragma unroll
    for (int t = 0; t < T; t++) {
        f32x4 z = {0.f, 0.f, 0.f, 0.f};
        acc[t] = z;
    }

#pragma unroll
    for (int s = 0; s < S; s++) {
        const float* ap = A + (size_t)(row0 + lm) * K + s * 32 + quad * 8;
        float4 x0 = *(const float4*)ap;
        float4 x1 = *(const float4*)(ap + 4);
        float v[8] = {x0.x, x0.y, x0.z, x0.w, x1.x, x1.y, x1.z, x1.w};
        s16x8 ah, al;
#pragma unroll
        for (int j = 0; j < 8; j++) {
            unsigned short h = f2bf(v[j]);
            float r = v[j] - bf2f(h);
            ah[j] = (short)h;
            al[j] = (short)f2bf(r);
        }
#pragma unroll
        for (int t = 0; t < T; t++) {
            const size_t fi = (size_t)((t * S + s) * 64 + lane) * 8;
            const s16x8 bh = *(const s16x8*)(Whi + fi);
            const s16x8 bl = *(const s16x8*)(Wlo + fi);
            acc[t] = __builtin_amdgcn_mfma_f32_16x16x32_bf16(ah, bh, acc[t], 0, 0, 0);
            acc[t] = __builtin_amdgcn_mfma_f32_16x16x32_bf16(al, bh, acc[t], 0, 0, 0);
            acc[t] = __builtin_amdgcn_mfma_f32_16x16x32_bf16(ah, bl, acc[t], 0, 0, 0);
        }
    }

    int orow = row0 + quad * 4;
#pragma unroll
    for (int t = 0; t < T; t++) {
        int col = t * 16 + lm;
        if (FOUT < F && col >= FOUT) continue;
        float bv = bias[col];
#pragma unroll
        for (int r = 0; r < 4; r++) {
            float vv = acc[t][r] + bv;
            if (RELU) vv = fmaxf(vv, 0.f);
            out[(size_t)(orow + r) * FOUT + col] = vv;
        }
    }
}

extern "C" void kernel_launch(void* const* d_in, const int* in_sizes, int n_in,
                              void* d_out, int out_size, void* d_ws, size_t ws_size,
                              hipStream_t stream) {
    const float* x  = (const float*)d_in[0];
    const int* ei   = (const int*)d_in[1];
    const float* W1 = (const float*)d_in[2];
    const float* b1 = (const float*)d_in[3];
    const float* W2 = (const float*)d_in[4];
    const float* b2 = (const float*)d_in[5];
    const float* W3 = (const float*)d_in[6];
    const float* b3 = (const float*)d_in[7];
    const float* W4 = (const float*)d_in[8];
    const float* b4 = (const float*)d_in[9];
    const float* Wl = (const float*)d_in[10];
    const float* bl = (const float*)d_in[11];
    float* out = (float*)d_out;

    const int* src = ei;
    const int* dst = ei + E_EDGES;

    // ---- Workspace: two 51.2 MB fp32 regions with disjoint lifetimes ----
    // R1: hF [N,128] (L1 agg), hF2 [N,128] (L2 agg), then h2b [N,256]
    // R2: h1 [N,128] | h1b [N,128], then h2 [N,256]
    char* ws = (char*)d_ws;
    const size_t R = (size_t)N_NODES * 256 * 4;   // 51.2e6 B
    float* R1 = (float*)ws;
    float* R2 = (float*)(ws + R);
    float* hF  = R1;                          // [N,128] layer-1 agg accumulator
    float* h1  = R2;                          // [N,128]
    float* h1b = R2 + (size_t)N_NODES * 128;  // [N,128]
    float* hF2 = R1;                          // [N,128] layer-2 agg accumulator
    float* h2  = R2;                          // [N,256]
    float* h2b = R1;                          // [N,256]
    size_t off = 2 * R;
    unsigned short* W1h = (unsigned short*)(ws + off); off += 16384 * 2;
    unsigned short* W1l = (unsigned short*)(ws + off); off += 16384 * 2;
    unsigned short* W2h = (unsigned short*)(ws + off); off += 16384 * 2;
    unsigned short* W2l = (unsigned short*)(ws + off); off += 16384 * 2;
    unsigned short* W3h = (unsigned short*)(ws + off); off += 32768 * 2;
    unsigned short* W3l = (unsigned short*)(ws + off); off += 32768 * 2;
    unsigned short* W4h = (unsigned short*)(ws + off); off += 65536 * 2;
    unsigned short* W4l = (unsigned short*)(ws + off); off += 65536 * 2;
    unsigned short* Wlh = (unsigned short*)(ws + off); off += 12288 * 2;
    unsigned short* Wll = (unsigned short*)(ws + off); off += 12288 * 2;
    (void)ws_size; (void)in_sizes; (void)n_in; (void)out_size;

    // Weight pre-split into hi/lo MFMA fragments (tiny)
    prep_w<<<8, 256, 0, stream>>>(W1, W1h, W1l, 128, 128, 128);
    prep_w<<<8, 256, 0, stream>>>(W2, W2h, W2l, 128, 128, 128);
    prep_w<<<16, 256, 0, stream>>>(W3, W3h, W3l, 128, 256, 256);
    prep_w<<<32, 256, 0, stream>>>(W4, W4h, W4l, 256, 256, 256);
    prep_w<<<6, 256, 0, stream>>>(Wl, Wlh, Wll, 256, 40, 48);

    const int scatN = E_EDGES * 32;           // 25.6M threads
    const size_t featB = (size_t)N_NODES * 128 * 4;

    // ---- Layer 1: hF = x + segsum(x[src] -> dst) ----
    hipMemcpyAsync(hF, x, featB, hipMemcpyDeviceToDevice, stream);
    scatter_add<<<(scatN + 255) / 256, 256, 0, stream>>>(x, src, dst, hF, scatN);
    gemm_split<128, 128, 128, true><<<782, 256, 0, stream>>>(hF, W1h, W1l, b1, h1);
    gemm_split<128, 128, 128, true><<<782, 256, 0, stream>>>(h1, W2h, W2l, b2, h1b);

    // ---- Layer 2: hF2 = h1b + segsum(h1b[src] -> dst) ----
    hipMemcpyAsync(hF2, h1b, featB, hipMemcpyDeviceToDevice, stream);
    scatter_add<<<(scatN + 255) / 256, 256, 0, stream>>>(h1b, src, dst, hF2, scatN);
    gemm_split<128, 256, 256, true><<<782, 256, 0, stream>>>(hF2, W3h, W3l, b3, h2);
    gemm_split<256, 256, 256, true><<<782, 256, 0, stream>>>(h2, W4h, W4l, b4, h2b);

    // ---- Final linear ----
    gemm_split<256, 48, 40, false><<<782, 256, 0, stream>>>(h2b, Wlh, Wll, bl, out);
}

// Round 4
// 491.806 us; speedup vs baseline: 5.9817x; 5.9817x over previous
//
#include <hip/hip_runtime.h>
#include <hip/hip_bf16.h>
#include <stdint.h>

#define N_NODES 50000
#define E_EDGES 800000

typedef short s16x8 __attribute__((ext_vector_type(8)));
typedef float f32x4 __attribute__((ext_vector_type(4)));

__device__ __forceinline__ float bf2f(unsigned int u) {
    return __uint_as_float(u << 16);
}
__device__ __forceinline__ unsigned short f2bf(float f) {
    unsigned int u = __float_as_uint(f);
    unsigned int r = (u + 0x7FFFu + ((u >> 16) & 1u)) >> 16;
    return (unsigned short)r;
}

// ---------------- CSR construction (once per launch, reused by both layers) ----

__global__ void hist_deg(const int* __restrict__ dst, int* __restrict__ deg) {
    int e = blockIdx.x * blockDim.x + threadIdx.x;
    if (e >= E_EDGES) return;
    atomicAdd(&deg[dst[e]], 1);
}

// Single-block exclusive scan of deg[50000] -> rowptr[50001] and cursor copy.
__global__ __launch_bounds__(1024) void scan_rowptr(const int* __restrict__ deg,
                                                    int* __restrict__ rowptr,
                                                    int* __restrict__ cursor) {
    __shared__ int wsum[16];
    int tid = threadIdx.x;
    int lane = tid & 63;
    int wid = tid >> 6;
    int running = 0;
    for (int chunk = 0; chunk < N_NODES; chunk += 1024) {
        int i = chunk + tid;
        int v = (i < N_NODES) ? deg[i] : 0;
        // wave-inclusive scan
        int x = v;
#pragma unroll
        for (int off = 1; off < 64; off <<= 1) {
            int t = __shfl_up(x, off);
            if (lane >= off) x += t;
        }
        if (lane == 63) wsum[wid] = x;
        __syncthreads();
        if (wid == 0 && lane < 16) {
            int w = wsum[lane];
#pragma unroll
            for (int off = 1; off < 16; off <<= 1) {
                int t = __shfl_up(w, off);
                if (lane >= off) w += t;
            }
            wsum[lane] = w;
        }
        __syncthreads();
        int wbase = (wid > 0) ? wsum[wid - 1] : 0;
        int excl = running + wbase + x - v;
        if (i < N_NODES) { rowptr[i] = excl; cursor[i] = excl; }
        running += wsum[15];
        __syncthreads();
    }
    if (tid == 0) rowptr[N_NODES] = E_EDGES;
}

__global__ void fill_csr(const int* __restrict__ src, const int* __restrict__ dst,
                         int* __restrict__ cursor, int* __restrict__ perm) {
    int e = blockIdx.x * blockDim.x + threadIdx.x;
    if (e >= E_EDGES) return;
    int d = dst[e];
    int pos = atomicAdd(&cursor[d], 1);
    perm[pos] = src[e];
}

// ---------------- Aggregation: out[n] = feat[n] + sum_{j in in(n)} feat[perm[j]]
// One wave per node, 2 fp32 channels per lane (128 ch).
__global__ __launch_bounds__(256) void gather_agg(
    const float* __restrict__ feat,
    const int* __restrict__ rowptr,
    const int* __restrict__ perm,
    float* __restrict__ out) {
    int node = (blockIdx.x * 256 + threadIdx.x) >> 6;
    if (node >= N_NODES) return;
    int lane = threadIdx.x & 63;
    const float2* fv = (const float2*)feat;
    float2 acc = fv[(size_t)node * 64 + lane];
    int beg = rowptr[node], end = rowptr[node + 1];
    for (int base = beg; base < end; base += 64) {
        int cnt = end - base; if (cnt > 64) cnt = 64;
        int pv = (base + lane < end) ? perm[base + lane] : 0;
        int j = 0;
        for (; j + 1 < cnt; j += 2) {
            int s0 = __shfl(pv, j);
            int s1 = __shfl(pv, j + 1);
            float2 v0 = fv[(size_t)s0 * 64 + lane];
            float2 v1 = fv[(size_t)s1 * 64 + lane];
            acc.x += v0.x + v1.x;
            acc.y += v0.y + v1.y;
        }
        if (j < cnt) {
            int s = __shfl(pv, j);
            float2 v = fv[(size_t)s * 64 + lane];
            acc.x += v.x;
            acc.y += v.y;
        }
    }
    ((float2*)out)[(size_t)node * 64 + lane] = acc;
}

// ---- Pre-split weight W[K][F] (fp32 row-major) into hi/lo bf16 MFMA B-frags:
__global__ void prep_w(const float* __restrict__ W,
                       unsigned short* __restrict__ Whi,
                       unsigned short* __restrict__ Wlo,
                       int K, int F, int Fpad) {
    int i = blockIdx.x * blockDim.x + threadIdx.x;
    int S = K / 32, T = Fpad / 16;
    int total = T * S * 64;
    if (i >= total) return;
    int lane = i & 63;
    int s = (i >> 6) % S;
    int t = (i >> 6) / S;
    int col = t * 16 + (lane & 15);
    int k0 = s * 32 + (lane >> 4) * 8;
    s16x8 vh, vl;
#pragma unroll
    for (int j = 0; j < 8; j++) {
        float w = (col < F) ? W[(size_t)(k0 + j) * F + col] : 0.f;
        unsigned short h = f2bf(w);
        float r = w - bf2f(h);
        vh[j] = (short)h;
        vl[j] = (short)f2bf(r);
    }
    *(s16x8*)(Whi + (size_t)i * 8) = vh;
    *(s16x8*)(Wlo + (size_t)i * 8) = vl;
}

// ---- GEMM with bf16 split-precision MFMA (3 mfma per tile).
template <int K, int F, int FOUT, bool RELU>
__global__ __launch_bounds__(256) void gemm_split(
    const float* __restrict__ A,
    const unsigned short* __restrict__ Whi,
    const unsigned short* __restrict__ Wlo,
    const float* __restrict__ bias,
    float* __restrict__ out) {
    constexpr int S = K / 32;
    constexpr int T = F / 16;
    int wave = threadIdx.x >> 6;
    int lane = threadIdx.x & 63;
    int row0 = blockIdx.x * 64 + wave * 16;
    if (row0 >= N_NODES) return;
    int lm = lane & 15;
    int quad = lane >> 4;

    f32x4 acc[T];
#pragma unroll
    for (int t = 0; t < T; t++) {
        f32x4 z = {0.f, 0.f, 0.f, 0.f};
        acc[t] = z;
    }

#pragma unroll
    for (int s = 0; s < S; s++) {
        const float* ap = A + (size_t)(row0 + lm) * K + s * 32 + quad * 8;
        float4 x0 = *(const float4*)ap;
        float4 x1 = *(const float4*)(ap + 4);
        float v[8] = {x0.x, x0.y, x0.z, x0.w, x1.x, x1.y, x1.z, x1.w};
        s16x8 ah, al;
#pragma unroll
        for (int j = 0; j < 8; j++) {
            unsigned short h = f2bf(v[j]);
            float r = v[j] - bf2f(h);
            ah[j] = (short)h;
            al[j] = (short)f2bf(r);
        }
#pragma unroll
        for (int t = 0; t < T; t++) {
            const size_t fi = (size_t)((t * S + s) * 64 + lane) * 8;
            const s16x8 bh = *(const s16x8*)(Whi + fi);
            const s16x8 bl = *(const s16x8*)(Wlo + fi);
            acc[t] = __builtin_amdgcn_mfma_f32_16x16x32_bf16(ah, bh, acc[t], 0, 0, 0);
            acc[t] = __builtin_amdgcn_mfma_f32_16x16x32_bf16(al, bh, acc[t], 0, 0, 0);
            acc[t] = __builtin_amdgcn_mfma_f32_16x16x32_bf16(ah, bl, acc[t], 0, 0, 0);
        }
    }

    int orow = row0 + quad * 4;
#pragma unroll
    for (int t = 0; t < T; t++) {
        int col = t * 16 + lm;
        if (FOUT < F && col >= FOUT) continue;
        float bv = bias[col];
#pragma unroll
        for (int r = 0; r < 4; r++) {
            float vv = acc[t][r] + bv;
            if (RELU) vv = fmaxf(vv, 0.f);
            out[(size_t)(orow + r) * FOUT + col] = vv;
        }
    }
}

extern "C" void kernel_launch(void* const* d_in, const int* in_sizes, int n_in,
                              void* d_out, int out_size, void* d_ws, size_t ws_size,
                              hipStream_t stream) {
    const float* x  = (const float*)d_in[0];
    const int* ei   = (const int*)d_in[1];
    const float* W1 = (const float*)d_in[2];
    const float* b1 = (const float*)d_in[3];
    const float* W2 = (const float*)d_in[4];
    const float* b2 = (const float*)d_in[5];
    const float* W3 = (const float*)d_in[6];
    const float* b3 = (const float*)d_in[7];
    const float* W4 = (const float*)d_in[8];
    const float* b4 = (const float*)d_in[9];
    const float* Wl = (const float*)d_in[10];
    const float* bl = (const float*)d_in[11];
    float* out = (float*)d_out;

    const int* src = ei;
    const int* dst = ei + E_EDGES;

    // ---- Workspace: two 51.2 MB fp32 regions (disjoint lifetimes) + CSR ----
    char* ws = (char*)d_ws;
    const size_t R = (size_t)N_NODES * 256 * 4;   // 51.2e6 B
    float* R1 = (float*)ws;
    float* R2 = (float*)(ws + R);
    float* hF  = R1;                          // [N,128] layer-1 agg accumulator
    float* h1  = R2;                          // [N,128]
    float* h1b = R2 + (size_t)N_NODES * 128;  // [N,128]
    float* hF2 = R1;                          // [N,128] layer-2 agg accumulator
    float* h2  = R2;                          // [N,256]
    float* h2b = R1;                          // [N,256]
    size_t off = 2 * R;
    unsigned short* W1h = (unsigned short*)(ws + off); off += 16384 * 2;
    unsigned short* W1l = (unsigned short*)(ws + off); off += 16384 * 2;
    unsigned short* W2h = (unsigned short*)(ws + off); off += 16384 * 2;
    unsigned short* W2l = (unsigned short*)(ws + off); off += 16384 * 2;
    unsigned short* W3h = (unsigned short*)(ws + off); off += 32768 * 2;
    unsigned short* W3l = (unsigned short*)(ws + off); off += 32768 * 2;
    unsigned short* W4h = (unsigned short*)(ws + off); off += 65536 * 2;
    unsigned short* W4l = (unsigned short*)(ws + off); off += 65536 * 2;
    unsigned short* Wlh = (unsigned short*)(ws + off); off += 12288 * 2;
    unsigned short* Wll = (unsigned short*)(ws + off); off += 12288 * 2;
    off = (off + 255) & ~(size_t)255;
    int* deg    = (int*)(ws + off); off += (size_t)(N_NODES + 1) * 4;
    int* cursor = (int*)(ws + off); off += (size_t)(N_NODES + 1) * 4;
    int* rowptr = (int*)(ws + off); off += (size_t)(N_NODES + 1) * 4;
    int* perm   = (int*)(ws + off); off += (size_t)E_EDGES * 4;
    (void)ws_size; (void)in_sizes; (void)n_in; (void)out_size;

    // ---- CSR build (once; reused by both layers) ----
    hipMemsetAsync(deg, 0, (size_t)(N_NODES + 1) * 4, stream);
    hist_deg<<<(E_EDGES + 255) / 256, 256, 0, stream>>>(dst, deg);
    scan_rowptr<<<1, 1024, 0, stream>>>(deg, rowptr, cursor);
    fill_csr<<<(E_EDGES + 255) / 256, 256, 0, stream>>>(src, dst, cursor, perm);

    // Weight pre-split into hi/lo MFMA fragments (tiny)
    prep_w<<<8, 256, 0, stream>>>(W1, W1h, W1l, 128, 128, 128);
    prep_w<<<8, 256, 0, stream>>>(W2, W2h, W2l, 128, 128, 128);
    prep_w<<<16, 256, 0, stream>>>(W3, W3h, W3l, 128, 256, 256);
    prep_w<<<32, 256, 0, stream>>>(W4, W4h, W4l, 256, 256, 256);
    prep_w<<<6, 256, 0, stream>>>(Wl, Wlh, Wll, 256, 40, 48);

    const int aggBlocks = (N_NODES * 64 + 255) / 256;   // 1 wave per node

    // ---- Layer 1: hF = x + segsum(x[src] -> dst) ----
    gather_agg<<<aggBlocks, 256, 0, stream>>>(x, rowptr, perm, hF);
    gemm_split<128, 128, 128, true><<<782, 256, 0, stream>>>(hF, W1h, W1l, b1, h1);
    gemm_split<128, 128, 128, true><<<782, 256, 0, stream>>>(h1, W2h, W2l, b2, h1b);

    // ---- Layer 2: hF2 = h1b + segsum(h1b[src] -> dst) ----
    gather_agg<<<aggBlocks, 256, 0, stream>>>(h1b, rowptr, perm, hF2);
    gemm_split<128, 256, 256, true><<<782, 256, 0, stream>>>(hF2, W3h, W3l, b3, h2);
    gemm_split<256, 256, 256, true><<<782, 256, 0, stream>>>(h2, W4h, W4l, b4, h2b);

    // ---- Final linear ----
    gemm_split<256, 48, 40, false><<<782, 256, 0, stream>>>(h2b, Wlh, Wll, bl, out);
}

// Round 5
// 449.526 us; speedup vs baseline: 6.5444x; 1.0941x over previous
//
#include <hip/hip_runtime.h>
#include <hip/hip_bf16.h>
#include <stdint.h>

#define N_NODES 50000
#define E_EDGES 800000

typedef short s16x8 __attribute__((ext_vector_type(8)));
typedef float f32x4 __attribute__((ext_vector_type(4)));

__device__ __forceinline__ float bf2f(unsigned int u) {
    return __uint_as_float(u << 16);
}
__device__ __forceinline__ unsigned short f2bf(float f) {
    unsigned int u = __float_as_uint(f);
    unsigned int r = (u + 0x7FFFu + ((u >> 16) & 1u)) >> 16;
    return (unsigned short)r;
}

// ---------------- CSR construction ----------------

__global__ void hist_deg(const int* __restrict__ dst, int* __restrict__ deg) {
    int e = blockIdx.x * blockDim.x + threadIdx.x;
    if (e >= E_EDGES) return;
    atomicAdd(&deg[dst[e]], 1);
}

// pass 1: per-block exclusive scan (local) + block totals
__global__ __launch_bounds__(1024) void scan1(const int* __restrict__ deg,
                                              int* __restrict__ lexcl,
                                              int* __restrict__ btot) {
    __shared__ int ws[16];
    int gid = blockIdx.x * 1024 + threadIdx.x;
    int lane = threadIdx.x & 63, wid = threadIdx.x >> 6;
    int v = (gid < N_NODES) ? deg[gid] : 0;
    int x = v;
#pragma unroll
    for (int off = 1; off < 64; off <<= 1) {
        int t = __shfl_up(x, off);
        if (lane >= off) x += t;
    }
    if (lane == 63) ws[wid] = x;
    __syncthreads();
    if (wid == 0 && lane < 16) {
        int w = ws[lane];
#pragma unroll
        for (int off = 1; off < 16; off <<= 1) {
            int t = __shfl_up(w, off);
            if (lane >= off) w += t;
        }
        ws[lane] = w;
    }
    __syncthreads();
    int excl = x - v + (wid ? ws[wid - 1] : 0);
    if (gid < N_NODES) lexcl[gid] = excl;
    if (threadIdx.x == 0) btot[blockIdx.x] = ws[15];
}

// pass 2: scan the 49 block totals (single wave)
__global__ void scan2(const int* __restrict__ btot, int* __restrict__ bbase,
                      int nb) {
    int lane = threadIdx.x;
    int v = (lane < nb) ? btot[lane] : 0;
    int x = v;
#pragma unroll
    for (int off = 1; off < 64; off <<= 1) {
        int t = __shfl_up(x, off);
        if (lane >= off) x += t;
    }
    if (lane < nb) bbase[lane] = x - v;
}

// pass 3: rowptr = lexcl + bbase; cursor copy
__global__ void scan3(const int* __restrict__ lexcl, const int* __restrict__ bbase,
                      int* __restrict__ rowptr, int* __restrict__ cursor) {
    int gid = blockIdx.x * blockDim.x + threadIdx.x;
    if (gid < N_NODES) {
        int r = lexcl[gid] + bbase[gid >> 10];
        rowptr[gid] = r;
        cursor[gid] = r;
    }
    if (gid == 0) rowptr[N_NODES] = E_EDGES;
}

__global__ void fill_csr(const int* __restrict__ src, const int* __restrict__ dst,
                         int* __restrict__ cursor, int* __restrict__ perm) {
    int e = blockIdx.x * blockDim.x + threadIdx.x;
    if (e >= E_EDGES) return;
    int d = dst[e];
    int pos = atomicAdd(&cursor[d], 1);
    perm[pos] = src[e];
}

// ---------------- Aggregation: out[n] = feat[n] + sum_{j in in(n)} feat[perm[j]]
// One node per 32-lane half-wave; 4 fp32 channels/lane (float4, 16 B);
// j-loop unrolled x4 -> 4 independent loads in flight per half-wave.
__global__ __launch_bounds__(256) void gather_agg(
    const float* __restrict__ feat,
    const int* __restrict__ rowptr,
    const int* __restrict__ perm,
    float* __restrict__ out) {
    int node = (blockIdx.x * 256 + threadIdx.x) >> 5;
    if (node >= N_NODES) return;
    int l32 = threadIdx.x & 31;
    int hb  = threadIdx.x & 32;          // half-select base for shfl
    const float4* fv = (const float4*)feat;
    float4 acc = fv[(size_t)node * 32 + l32];
    int beg = rowptr[node], end = rowptr[node + 1];
    for (int base = beg; base < end; base += 32) {
        int cnt = end - base; if (cnt > 32) cnt = 32;
        int pv = (base + l32 < end) ? perm[base + l32] : 0;
        int j = 0;
        for (; j + 4 <= cnt; j += 4) {
            int s0 = __shfl(pv, hb | (j + 0));
            int s1 = __shfl(pv, hb | (j + 1));
            int s2 = __shfl(pv, hb | (j + 2));
            int s3 = __shfl(pv, hb | (j + 3));
            float4 v0 = fv[(size_t)s0 * 32 + l32];
            float4 v1 = fv[(size_t)s1 * 32 + l32];
            float4 v2 = fv[(size_t)s2 * 32 + l32];
            float4 v3 = fv[(size_t)s3 * 32 + l32];
            acc.x += (v0.x + v1.x) + (v2.x + v3.x);
            acc.y += (v0.y + v1.y) + (v2.y + v3.y);
            acc.z += (v0.z + v1.z) + (v2.z + v3.z);
            acc.w += (v0.w + v1.w) + (v2.w + v3.w);
        }
        for (; j < cnt; j++) {
            int s = __shfl(pv, hb | j);
            float4 v = fv[(size_t)s * 32 + l32];
            acc.x += v.x; acc.y += v.y; acc.z += v.z; acc.w += v.w;
        }
    }
    ((float4*)out)[(size_t)node * 32 + l32] = acc;
}

// ---- Weight pre-split (fused, all 5 weights in one launch) ----
__device__ __forceinline__ void prep_one(const float* __restrict__ W,
                                         unsigned short* __restrict__ Whi,
                                         unsigned short* __restrict__ Wlo,
                                         int K, int F, int Fpad, int i) {
    int S = K / 32, T = Fpad / 16;
    int total = T * S * 64;
    if (i >= total) return;
    int lane = i & 63;
    int s = (i >> 6) % S;
    int t = (i >> 6) / S;
    int col = t * 16 + (lane & 15);
    int k0 = s * 32 + (lane >> 4) * 8;
    s16x8 vh, vl;
#pragma unroll
    for (int j = 0; j < 8; j++) {
        float w = (col < F) ? W[(size_t)(k0 + j) * F + col] : 0.f;
        unsigned short h = f2bf(w);
        float r = w - bf2f(h);
        vh[j] = (short)h;
        vl[j] = (short)f2bf(r);
    }
    *(s16x8*)(Whi + (size_t)i * 8) = vh;
    *(s16x8*)(Wlo + (size_t)i * 8) = vl;
}

__global__ void prep_all(const float* W1, const float* W2, const float* W3,
                         const float* W4, const float* Wl,
                         unsigned short* W1h, unsigned short* W1l,
                         unsigned short* W2h, unsigned short* W2l,
                         unsigned short* W3h, unsigned short* W3l,
                         unsigned short* W4h, unsigned short* W4l,
                         unsigned short* Wlh, unsigned short* Wll) {
    int b = blockIdx.x, t = threadIdx.x;
    if (b < 8)       prep_one(W1, W1h, W1l, 128, 128, 128, b * 256 + t);
    else if (b < 16) prep_one(W2, W2h, W2l, 128, 128, 128, (b - 8) * 256 + t);
    else if (b < 32) prep_one(W3, W3h, W3l, 128, 256, 256, (b - 16) * 256 + t);
    else if (b < 64) prep_one(W4, W4h, W4l, 256, 256, 256, (b - 32) * 256 + t);
    else             prep_one(Wl, Wlh, Wll, 256, 40, 48, (b - 64) * 256 + t);
}

// ---- GEMM with bf16 split-precision MFMA (3 mfma per tile). ----
template <int K, int F, int FOUT, bool RELU>
__global__ __launch_bounds__(256) void gemm_split(
    const float* __restrict__ A,
    const unsigned short* __restrict__ Whi,
    const unsigned short* __restrict__ Wlo,
    const float* __restrict__ bias,
    float* __restrict__ out) {
    constexpr int S = K / 32;
    constexpr int T = F / 16;
    int wave = threadIdx.x >> 6;
    int lane = threadIdx.x & 63;
    int row0 = blockIdx.x * 64 + wave * 16;
    if (row0 >= N_NODES) return;
    int lm = lane & 15;
    int quad = lane >> 4;

    f32x4 acc[T];
#pragma unroll
    for (int t = 0; t < T; t++) {
        f32x4 z = {0.f, 0.f, 0.f, 0.f};
        acc[t] = z;
    }

#pragma unroll
    for (int s = 0; s < S; s++) {
        const float* ap = A + (size_t)(row0 + lm) * K + s * 32 + quad * 8;
        float4 x0 = *(const float4*)ap;
        float4 x1 = *(const float4*)(ap + 4);
        float v[8] = {x0.x, x0.y, x0.z, x0.w, x1.x, x1.y, x1.z, x1.w};
        s16x8 ah, al;
#pragma unroll
        for (int j = 0; j < 8; j++) {
            unsigned short h = f2bf(v[j]);
            float r = v[j] - bf2f(h);
            ah[j] = (short)h;
            al[j] = (short)f2bf(r);
        }
#pragma unroll
        for (int t = 0; t < T; t++) {
            const size_t fi = (size_t)((t * S + s) * 64 + lane) * 8;
            const s16x8 bh = *(const s16x8*)(Whi + fi);
            const s16x8 bl = *(const s16x8*)(Wlo + fi);
            acc[t] = __builtin_amdgcn_mfma_f32_16x16x32_bf16(ah, bh, acc[t], 0, 0, 0);
            acc[t] = __builtin_amdgcn_mfma_f32_16x16x32_bf16(al, bh, acc[t], 0, 0, 0);
            acc[t] = __builtin_amdgcn_mfma_f32_16x16x32_bf16(ah, bl, acc[t], 0, 0, 0);
        }
    }

    int orow = row0 + quad * 4;
#pragma unroll
    for (int t = 0; t < T; t++) {
        int col = t * 16 + lm;
        if (FOUT < F && col >= FOUT) continue;
        float bv = bias[col];
#pragma unroll
        for (int r = 0; r < 4; r++) {
            float vv = acc[t][r] + bv;
            if (RELU) vv = fmaxf(vv, 0.f);
            out[(size_t)(orow + r) * FOUT + col] = vv;
        }
    }
}

extern "C" void kernel_launch(void* const* d_in, const int* in_sizes, int n_in,
                              void* d_out, int out_size, void* d_ws, size_t ws_size,
                              hipStream_t stream) {
    const float* x  = (const float*)d_in[0];
    const int* ei   = (const int*)d_in[1];
    const float* W1 = (const float*)d_in[2];
    const float* b1 = (const float*)d_in[3];
    const float* W2 = (const float*)d_in[4];
    const float* b2 = (const float*)d_in[5];
    const float* W3 = (const float*)d_in[6];
    const float* b3 = (const float*)d_in[7];
    const float* W4 = (const float*)d_in[8];
    const float* b4 = (const float*)d_in[9];
    const float* Wl = (const float*)d_in[10];
    const float* bl = (const float*)d_in[11];
    float* out = (float*)d_out;

    const int* src = ei;
    const int* dst = ei + E_EDGES;

    // ---- Workspace: two 51.2 MB fp32 regions (disjoint lifetimes) + CSR ----
    char* ws = (char*)d_ws;
    const size_t R = (size_t)N_NODES * 256 * 4;   // 51.2e6 B
    float* R1 = (float*)ws;
    float* R2 = (float*)(ws + R);
    float* hF  = R1;                          // [N,128] layer-1 agg accumulator
    float* h1  = R2;                          // [N,128]
    float* h1b = R2 + (size_t)N_NODES * 128;  // [N,128]
    float* hF2 = R1;                          // [N,128] layer-2 agg accumulator
    float* h2  = R2;                          // [N,256]
    float* h2b = R1;                          // [N,256]
    size_t off = 2 * R;
    unsigned short* W1h = (unsigned short*)(ws + off); off += 16384 * 2;
    unsigned short* W1l = (unsigned short*)(ws + off); off += 16384 * 2;
    unsigned short* W2h = (unsigned short*)(ws + off); off += 16384 * 2;
    unsigned short* W2l = (unsigned short*)(ws + off); off += 16384 * 2;
    unsigned short* W3h = (unsigned short*)(ws + off); off += 32768 * 2;
    unsigned short* W3l = (unsigned short*)(ws + off); off += 32768 * 2;
    unsigned short* W4h = (unsigned short*)(ws + off); off += 65536 * 2;
    unsigned short* W4l = (unsigned short*)(ws + off); off += 65536 * 2;
    unsigned short* Wlh = (unsigned short*)(ws + off); off += 12288 * 2;
    unsigned short* Wll = (unsigned short*)(ws + off); off += 12288 * 2;
    off = (off + 255) & ~(size_t)255;
    int* deg    = (int*)(ws + off); off += (size_t)(N_NODES + 1) * 4;
    int* cursor = (int*)(ws + off); off += (size_t)(N_NODES + 1) * 4;
    int* rowptr = (int*)(ws + off); off += (size_t)(N_NODES + 1) * 4;
    int* perm   = (int*)(ws + off); off += (size_t)E_EDGES * 4;
    int* lexcl  = (int*)(ws + off); off += (size_t)N_NODES * 4;
    int* btot   = (int*)(ws + off); off += 64 * 4;
    int* bbase  = (int*)(ws + off); off += 64 * 4;
    (void)ws_size; (void)in_sizes; (void)n_in; (void)out_size;

    const int NB = (N_NODES + 1023) / 1024;   // 49 scan blocks

    // ---- CSR build (parallel scan) ----
    hipMemsetAsync(deg, 0, (size_t)(N_NODES + 1) * 4, stream);
    hist_deg<<<(E_EDGES + 255) / 256, 256, 0, stream>>>(dst, deg);
    scan1<<<NB, 1024, 0, stream>>>(deg, lexcl, btot);
    scan2<<<1, 64, 0, stream>>>(btot, bbase, NB);
    scan3<<<(N_NODES + 255) / 256, 256, 0, stream>>>(lexcl, bbase, rowptr, cursor);
    fill_csr<<<(E_EDGES + 255) / 256, 256, 0, stream>>>(src, dst, cursor, perm);

    // ---- Weight pre-split (one launch) ----
    prep_all<<<70, 256, 0, stream>>>(W1, W2, W3, W4, Wl,
                                     W1h, W1l, W2h, W2l, W3h, W3l,
                                     W4h, W4l, Wlh, Wll);

    const int aggBlocks = (N_NODES * 32 + 255) / 256;   // 1 node / 32 lanes

    // ---- Layer 1 ----
    gather_agg<<<aggBlocks, 256, 0, stream>>>(x, rowptr, perm, hF);
    gemm_split<128, 128, 128, true><<<782, 256, 0, stream>>>(hF, W1h, W1l, b1, h1);
    gemm_split<128, 128, 128, true><<<782, 256, 0, stream>>>(h1, W2h, W2l, b2, h1b);

    // ---- Layer 2 ----
    gather_agg<<<aggBlocks, 256, 0, stream>>>(h1b, rowptr, perm, hF2);
    gemm_split<128, 256, 256, true><<<782, 256, 0, stream>>>(hF2, W3h, W3l, b3, h2);
    gemm_split<256, 256, 256, true><<<782, 256, 0, stream>>>(h2, W4h, W4l, b4, h2b);

    // ---- Final linear ----
    gemm_split<256, 48, 40, false><<<782, 256, 0, stream>>>(h2b, Wlh, Wll, bl, out);
}